// Round 5
// baseline (385.761 us; speedup 1.0000x reference)
//
#include <hip/hip_runtime.h>
#include <hip/hip_bf16.h>

// TinyCondEpsNet: out = relu([y|x|te] @ W1^T + b1) @ W2^T + b2
// B=524288, X=128, TE=32, IN=161, H=64.
// K-permutation: k 0..127 = x, 128..159 = te, 160 = y_t, 161 = const 1.0
// (folds fc1_bias), 162..191 = 0 (pad to 6 K-steps of 32).
//
// v2: x staged global->LDS via global_load_lds (dense 1KiB/instr) with
// both-sides XOR chunk swizzle (c ^= r&7) so fragment ds_read_b128 is
// conflict-minimal. One wave = one 16-row M-tile, wave-private LDS region,
// no barriers. Setup kernels fused.

typedef __bf16 bf16x8 __attribute__((ext_vector_type(8)));
typedef float  f32x4  __attribute__((ext_vector_type(4)));

#define NROWS   524288
#define KSTEPS  6
#define NTILES  4
// d_ws layout: [0, 24576) W1 B-fragments; [24576, +64000) te table bf16[1000][32]

static __device__ inline unsigned short f2bf(float x) {
    union { float f; unsigned u; } v; v.f = x;
    unsigned r = v.u + 0x7FFFu + ((v.u >> 16) & 1u);   // round-to-nearest-even
    return (unsigned short)(r >> 16);
}

static __device__ inline bf16x8 cvt8(float4 a, float4 b) {
    uint4 r;
    r.x = (unsigned)f2bf(a.x) | ((unsigned)f2bf(a.y) << 16);
    r.y = (unsigned)f2bf(a.z) | ((unsigned)f2bf(a.w) << 16);
    r.z = (unsigned)f2bf(b.x) | ((unsigned)f2bf(b.y) << 16);
    r.w = (unsigned)f2bf(b.z) | ((unsigned)f2bf(b.w) << 16);
    return __builtin_bit_cast(bf16x8, r);
}

static __device__ inline void gload_lds16(const void* g, void* l) {
    __builtin_amdgcn_global_load_lds(
        (const __attribute__((address_space(1))) unsigned int*)g,
        (__attribute__((address_space(3))) unsigned int*)l, 16, 0, 0);
}

// ---- fused setup: W1 fragments + sinusoidal table ----
// wfrag: frag f = n*6+s, lane l: B[k][col], col = 16n + (l&15), k = 32s + 8*(l>>4) + j
// tetab: bf16[1000][32]: [t][0..15]=sin(t*f_j), [t][16..31]=cos(t*f_j)
__global__ void setup_tables(const float* __restrict__ w1, const float* __restrict__ b1,
                             unsigned short* __restrict__ wf, unsigned short* __restrict__ tab) {
    int tid = blockIdx.x * blockDim.x + threadIdx.x;   // 64 blocks * 256 = 16384
    if (tid < 1536) {
        int l  = tid & 63;
        int fs = tid >> 6;          // 0..23
        int n  = fs / 6;
        int s  = fs % 6;
        int col = 16 * n + (l & 15);
        int g   = l >> 4;
        unsigned short vals[8] __attribute__((aligned(16)));
        #pragma unroll
        for (int j = 0; j < 8; ++j) {
            int k = 32 * s + 8 * g + j;
            float v;
            if      (k < 160)  v = w1[col * 161 + k + 1]; // x cols 1..128, te cols 129..160
            else if (k == 160) v = w1[col * 161 + 0];     // y_t col 0
            else if (k == 161) v = b1[col];               // bias via const-1 input
            else               v = 0.0f;
            vals[j] = f2bf(v);
        }
        ((uint4*)wf)[tid] = *(const uint4*)vals;
    }
    if (tid < 16000) {
        int t = tid >> 4;
        int j = tid & 15;
        float freq = expf((-9.2103403719761836f * (float)j) * 0.0625f);  // exp(-ln(1e4)*j/16)
        float a    = (float)t * freq;
        tab[t * 32 + j]      = f2bf(sinf(a));
        tab[t * 32 + 16 + j] = f2bf(cosf(a));
    }
}

// ---- main: block = 64 rows, 4 waves, 1 M-tile/wave, wave-private LDS ----
__global__ __launch_bounds__(256, 4) void mlp_kernel(
    const float* __restrict__ y_t, const int* __restrict__ t, const float* __restrict__ x,
    const float* __restrict__ w2, const float* __restrict__ b2p,
    const unsigned short* __restrict__ wfrag, const unsigned short* __restrict__ tetab,
    float* __restrict__ out)
{
    __shared__ __align__(16) float ldsx[64 * 128];     // 32 KiB: 4 tiles * 16 rows * 128 f32
    const int tid = threadIdx.x;
    const int l   = tid & 63;
    const int wv  = tid >> 6;    // 0..3 = this wave's M-tile
    const int r   = l & 15;      // A-frag row within tile / N-col of D
    const int g   = l >> 4;      // k-group
    const long long trow0 = (long long)blockIdx.x * 64 + wv * 16;   // tile's first batch row
    const long long arow  = trow0 + r;                              // this lane's batch row

    // per-tile scalars (issue early; drained by the vmcnt(0) below)
    int   tval = t[arow];
    float yv   = y_t[arow];

    float w2f[4];
    #pragma unroll
    for (int n = 0; n < NTILES; ++n) w2f[n] = w2[16 * n + r];
    const float b2 = b2p[0];

    // ---- stage x tile -> LDS: dense 1KiB/instr, XOR-swizzled global source ----
    // LDS chunk (rowrel*32 + c) receives global chunk (rowrel*32 + (c ^ (rowrel&7))).
    {
        const int rr = l >> 5;        // row within the 2-row unit
        const int c  = l & 31;        // 16B chunk within row
        #pragma unroll
        for (int i = 0; i < 8; ++i) {
            const int rowrel = 2 * i + rr;                    // 0..15
            const int csrc   = c ^ (rowrel & 7);
            const float* src = x + (trow0 + rowrel) * 128 + csrc * 4;
            gload_lds16(src, (void*)(ldsx + wv * 2048 + i * 256));
        }
    }
    asm volatile("s_waitcnt vmcnt(0)" ::: "memory");

    // ---- A fragments from LDS (swizzled read) ----
    bf16x8 af[KSTEPS];
    {
        const float4* lx = (const float4*)ldsx;
        const int base = wv * 512 + r * 32;
        const int sw   = r & 7;
        #pragma unroll
        for (int s = 0; s < 4; ++s) {                  // k = 0..127: x
            int c0 = 8 * s + 2 * g;
            float4 a = lx[base + ((c0    ) ^ sw)];
            float4 b = lx[base + ((c0 + 1) ^ sw)];
            af[s] = cvt8(a, b);
        }
    }
    {                                                  // k = 128..159: te gather (L2-resident)
        tval = tval < 0 ? 0 : (tval > 999 ? 999 : tval);
        af[4] = *(const bf16x8*)(tetab + tval * 32 + 8 * g);
    }
    {                                                  // k = 160..191: y_t, 1.0, zeros
        uint4 u = make_uint4(0u, 0u, 0u, 0u);
        if (g == 0) u.x = (unsigned)f2bf(yv) | (0x3F80u << 16);
        af[5] = __builtin_bit_cast(bf16x8, u);
    }

    // ---- MFMA: h[16 rows][64 units] ----
    const bf16x8* __restrict__ wfv = (const bf16x8*)wfrag;
    f32x4 acc[NTILES];
    #pragma unroll
    for (int n = 0; n < NTILES; ++n) acc[n] = (f32x4){0.f, 0.f, 0.f, 0.f};
    #pragma unroll
    for (int n = 0; n < NTILES; ++n)
        #pragma unroll
        for (int s = 0; s < KSTEPS; ++s)
            acc[n] = __builtin_amdgcn_mfma_f32_16x16x32_bf16(
                af[s], wfv[(n * 6 + s) * 64 + l], acc[n], 0, 0, 0);

    // ---- epilogue: relu, dot with w2, reduce over 16 lanes (r), store ----
    // D layout: h[row = 4g+v][col = 16n + r] in acc[n][v]
    float4 p;
    float* pp = &p.x;
    #pragma unroll
    for (int v = 0; v < 4; ++v) {
        float pv = 0.f;
        #pragma unroll
        for (int n = 0; n < NTILES; ++n) pv += w2f[n] * fmaxf(acc[n][v], 0.f);
        pv += __shfl_xor(pv, 1);
        pv += __shfl_xor(pv, 2);
        pv += __shfl_xor(pv, 4);
        pv += __shfl_xor(pv, 8);
        pp[v] = pv + b2;
    }
    if (r == 0) {
        *(float4*)(out + trow0 + 4 * g) = p;
    }
}

extern "C" void kernel_launch(void* const* d_in, const int* in_sizes, int n_in,
                              void* d_out, int out_size, void* d_ws, size_t ws_size,
                              hipStream_t stream) {
    const float* y_t = (const float*)d_in[0];
    const int*   t   = (const int*)  d_in[1];
    const float* x   = (const float*)d_in[2];
    const float* w1  = (const float*)d_in[3];
    const float* b1  = (const float*)d_in[4];
    const float* w2  = (const float*)d_in[5];
    const float* b2  = (const float*)d_in[6];

    unsigned short* wfrag = (unsigned short*)d_ws;
    unsigned short* tetab = wfrag + 12288;   // 24576 bytes in

    setup_tables<<<64, 256, 0, stream>>>(w1, b1, wfrag, tetab);
    mlp_kernel<<<NROWS / 64, 256, 0, stream>>>(y_t, t, x, w2, b2, wfrag, tetab, (float*)d_out);
}

// Round 6
// 377.703 us; speedup vs baseline: 1.0213x; 1.0213x over previous
//
#include <hip/hip_runtime.h>
#include <hip/hip_bf16.h>

// TinyCondEpsNet: out = relu([y|x|te] @ W1^T + b1) @ W2^T + b2
// B=524288, X=128, TE=32, IN=161, H=64.
// K-permutation: k 0..127 = x, 128..159 = te, 160 = y_t, 161 = const 1.0
// (folds fc1_bias), 162..191 = 0 (pad to 6 K-steps of 32).
//
// v3: persistent pipelined streaming. Grid = 512 blocks (2/CU), each wave
// owns 16 tiles (16 rows each) and software-pipelines: prefetch tile k+1
// (registers, no LDS) while computing tile k. Keeps ~8 KB/wave outstanding
// through the compute phase -> sustained HBM request pressure instead of
// one-shot issue+drain. Weights/te-table are L1/L2-resident loads.

typedef __bf16 bf16x8 __attribute__((ext_vector_type(8)));
typedef float  f32x4  __attribute__((ext_vector_type(4)));

#define NROWS   524288
#define KSTEPS  6
#define NTILES  4
#define GRID    512
#define ITERS   16          // tiles per wave: 512 blk * 4 waves * 16 = 32768 tiles
// d_ws layout: [0, 24576) W1 B-fragments; [24576, +64000) te table bf16[1000][32]

static __device__ inline unsigned short f2bf(float x) {
    union { float f; unsigned u; } v; v.f = x;
    unsigned r = v.u + 0x7FFFu + ((v.u >> 16) & 1u);   // round-to-nearest-even
    return (unsigned short)(r >> 16);
}

static __device__ inline bf16x8 cvt8(float4 a, float4 b) {
    uint4 r;
    r.x = (unsigned)f2bf(a.x) | ((unsigned)f2bf(a.y) << 16);
    r.y = (unsigned)f2bf(a.z) | ((unsigned)f2bf(a.w) << 16);
    r.z = (unsigned)f2bf(b.x) | ((unsigned)f2bf(b.y) << 16);
    r.w = (unsigned)f2bf(b.z) | ((unsigned)f2bf(b.w) << 16);
    return __builtin_bit_cast(bf16x8, r);
}

// ---- fused setup: W1 fragments + sinusoidal table ----
// wfrag: frag f = n*6+s, lane l: B[k][col], col = 16n + (l&15), k = 32s + 8*(l>>4) + j
// tetab: bf16[1000][32]: [t][0..15]=sin(t*f_j), [t][16..31]=cos(t*f_j)
__global__ void setup_tables(const float* __restrict__ w1, const float* __restrict__ b1,
                             unsigned short* __restrict__ wf, unsigned short* __restrict__ tab) {
    int tid = blockIdx.x * blockDim.x + threadIdx.x;   // 64 blocks * 256 = 16384
    if (tid < 1536) {
        int l  = tid & 63;
        int fs = tid >> 6;          // 0..23
        int n  = fs / 6;
        int s  = fs % 6;
        int col = 16 * n + (l & 15);
        int g   = l >> 4;
        unsigned short vals[8] __attribute__((aligned(16)));
        #pragma unroll
        for (int j = 0; j < 8; ++j) {
            int k = 32 * s + 8 * g + j;
            float v;
            if      (k < 160)  v = w1[col * 161 + k + 1]; // x cols 1..128, te cols 129..160
            else if (k == 160) v = w1[col * 161 + 0];     // y_t col 0
            else if (k == 161) v = b1[col];               // bias via const-1 input
            else               v = 0.0f;
            vals[j] = f2bf(v);
        }
        ((uint4*)wf)[tid] = *(const uint4*)vals;
    }
    if (tid < 16000) {
        int t = tid >> 4;
        int j = tid & 15;
        float freq = expf((-9.2103403719761836f * (float)j) * 0.0625f);  // exp(-ln(1e4)*j/16)
        float a    = (float)t * freq;
        tab[t * 32 + j]      = f2bf(sinf(a));
        tab[t * 32 + 16 + j] = f2bf(cosf(a));
    }
}

static __device__ inline int clamp_t(int tv) {
    return tv < 0 ? 0 : (tv > 999 ? 999 : tv);
}

// ---- main: persistent, register-staged, depth-1 software pipeline ----
__global__ __launch_bounds__(256, 2) void mlp_kernel(
    const float* __restrict__ y_t, const int* __restrict__ t, const float* __restrict__ x,
    const float* __restrict__ w2, const float* __restrict__ b2p,
    const unsigned short* __restrict__ wfrag, const unsigned short* __restrict__ tetab,
    float* __restrict__ out)
{
    const int tid = threadIdx.x;
    const int l   = tid & 63;
    const int wv  = tid >> 6;    // wave in block
    const int r   = l & 15;      // row within tile / reduce group
    const int g   = l >> 4;      // k-group

    float w2f[4];
    #pragma unroll
    for (int n = 0; n < NTILES; ++n) w2f[n] = w2[16 * n + r];
    const float b2 = b2p[0];
    const bf16x8* __restrict__ wfv = (const bf16x8*)wfrag;

    // wave's tile sequence: tile = blockIdx.x*64 + wv + 4*i  (i = 0..15)
    long long tile = (long long)blockIdx.x * 64 + wv;
    long long row  = tile * 16 + r;

    // ---- prologue: load tile 0 into current regs ----
    float4 cx[8];
    {
        const float4* xr = (const float4*)(x + row * 128);
        #pragma unroll
        for (int s = 0; s < 4; ++s) {
            cx[2 * s]     = xr[8 * s + 2 * g];
            cx[2 * s + 1] = xr[8 * s + 2 * g + 1];
        }
    }
    int   t_cur = clamp_t(t[row]);
    float y_cur = y_t[row];

    #pragma unroll 1
    for (int i = 0; i < ITERS; ++i) {
        // ---- prefetch tile i+1 (stays outstanding through this tile's compute) ----
        float4 nx[8];
        int    t_nxt = 0;
        float  y_nxt = 0.f;
        const bool has_next = (i + 1 < ITERS);
        if (has_next) {
            const long long nrow = row + 64;               // tile+4 -> +64 rows
            const float4* xr = (const float4*)(x + nrow * 128);
            #pragma unroll
            for (int s = 0; s < 4; ++s) {
                nx[2 * s]     = xr[8 * s + 2 * g];
                nx[2 * s + 1] = xr[8 * s + 2 * g + 1];
            }
            t_nxt = t[nrow];
            y_nxt = y_t[nrow];
        }

        // ---- A fragments for current tile ----
        bf16x8 af[KSTEPS];
        #pragma unroll
        for (int s = 0; s < 4; ++s) af[s] = cvt8(cx[2 * s], cx[2 * s + 1]);
        af[4] = *(const bf16x8*)(tetab + t_cur * 32 + 8 * g);   // t_cur from prior iter
        {
            uint4 u = make_uint4(0u, 0u, 0u, 0u);
            if (g == 0) u.x = (unsigned)f2bf(y_cur) | (0x3F80u << 16);
            af[5] = __builtin_bit_cast(bf16x8, u);
        }

        // ---- MFMA: h[16 rows][64 units] ----
        f32x4 acc[NTILES];
        #pragma unroll
        for (int n = 0; n < NTILES; ++n) acc[n] = (f32x4){0.f, 0.f, 0.f, 0.f};
        #pragma unroll
        for (int n = 0; n < NTILES; ++n)
            #pragma unroll
            for (int s = 0; s < KSTEPS; ++s)
                acc[n] = __builtin_amdgcn_mfma_f32_16x16x32_bf16(
                    af[s], wfv[(n * 6 + s) * 64 + l], acc[n], 0, 0, 0);

        // ---- epilogue: relu, dot w2, 16-lane reduce, store ----
        // D layout: h[row = 4g+v][col = 16n + r] in acc[n][v]
        float4 p;
        float* pp = &p.x;
        #pragma unroll
        for (int v = 0; v < 4; ++v) {
            float pv = 0.f;
            #pragma unroll
            for (int n = 0; n < NTILES; ++n) pv += w2f[n] * fmaxf(acc[n][v], 0.f);
            pv += __shfl_xor(pv, 1);
            pv += __shfl_xor(pv, 2);
            pv += __shfl_xor(pv, 4);
            pv += __shfl_xor(pv, 8);
            pp[v] = pv + b2;
        }
        if (r == 0) {
            *(float4*)(out + tile * 16 + 4 * g) = p;
        }

        // ---- rotate pipeline ----
        if (has_next) {
            #pragma unroll
            for (int s = 0; s < 8; ++s) cx[s] = nx[s];
            t_cur = clamp_t(t_nxt);
            y_cur = y_nxt;
        }
        tile += 4;
        row  += 64;
    }
}

extern "C" void kernel_launch(void* const* d_in, const int* in_sizes, int n_in,
                              void* d_out, int out_size, void* d_ws, size_t ws_size,
                              hipStream_t stream) {
    const float* y_t = (const float*)d_in[0];
    const int*   t   = (const int*)  d_in[1];
    const float* x   = (const float*)d_in[2];
    const float* w1  = (const float*)d_in[3];
    const float* b1  = (const float*)d_in[4];
    const float* w2  = (const float*)d_in[5];
    const float* b2  = (const float*)d_in[6];

    unsigned short* wfrag = (unsigned short*)d_ws;
    unsigned short* tetab = wfrag + 12288;   // 24576 bytes in

    setup_tables<<<64, 256, 0, stream>>>(w1, b1, wfrag, tetab);
    mlp_kernel<<<GRID, 256, 0, stream>>>(y_t, t, x, w2, b2, wfrag, tetab, (float*)d_out);
}